// Round 13
// baseline (80.438 us; speedup 1.0000x reference)
//
#include <hip/hip_runtime.h>
#include <math.h>

#define NROWS 8192
#define DIM 64
#define KNBR 200
#define BN_EPS 1e-5f
#define BIGF 3.402823466e38f

typedef float f4 __attribute__((ext_vector_type(4)));

// ---------- wave-level helpers (wave = 64 lanes) ----------

__device__ __forceinline__ float matvec64(const float* xlds,
                                          const float* __restrict__ W,
                                          int lane) {
    float acc = 0.f;
#pragma unroll
    for (int i4 = 0; i4 < 16; ++i4) {
        float4 xv = *(const float4*)(xlds + i4 * 4);
        acc = fmaf(xv.x, W[(i4 * 4 + 0) * 64 + lane], acc);
        acc = fmaf(xv.y, W[(i4 * 4 + 1) * 64 + lane], acc);
        acc = fmaf(xv.z, W[(i4 * 4 + 2) * 64 + lane], acc);
        acc = fmaf(xv.w, W[(i4 * 4 + 3) * 64 + lane], acc);
    }
    return acc;
}

__device__ __forceinline__ float matvec128(const float* xlds,
                                           const float* __restrict__ W,
                                           int lane) {
    float acc = 0.f;
#pragma unroll
    for (int i4 = 0; i4 < 32; ++i4) {
        float4 xv = *(const float4*)(xlds + i4 * 4);
        acc = fmaf(xv.x, W[(i4 * 4 + 0) * 64 + lane], acc);
        acc = fmaf(xv.y, W[(i4 * 4 + 1) * 64 + lane], acc);
        acc = fmaf(xv.z, W[(i4 * 4 + 2) * 64 + lane], acc);
        acc = fmaf(xv.w, W[(i4 * 4 + 3) * 64 + lane], acc);
    }
    return acc;
}

__device__ __forceinline__ float d2part4(const f4 a, const f4 b) {
    const float dx = a.x - b.x, dy = a.y - b.y, dz = a.z - b.z, dw = a.w - b.w;
    float d2 = dx * dx;
    d2 = fmaf(dy, dy, d2);
    d2 = fmaf(dz, dz, d2);
    d2 = fmaf(dw, dw, d2);
    return d2;
}

__device__ __forceinline__ float sum16(float v) {
    v += __shfl_xor(v, 1);
    v += __shfl_xor(v, 2);
    v += __shfl_xor(v, 4);
    v += __shfl_xor(v, 8);
    return v;
}

// ---------- fused kernel: one wave per row (R6 structure) ----------
// ONLY change vs R6: all scattered v_embed / nbr_idx reads use
// __builtin_nontemporal_load (MUBUF `nt`) to bypass L1 allocation --
// testing the L1-MSHR/thrash hypothesis for the 58us gather invariant.
__global__ __launch_bounds__(256) void fused_rows(
    const float* __restrict__ v_embed,
    const float* __restrict__ u1p, const float* __restrict__ u2p,
    const float* __restrict__ u3p, const float* __restrict__ u4p,
    const float* __restrict__ evp,
    const float* __restrict__ w_ur1, const float* __restrict__ b_ur1,
    const float* __restrict__ w_ur2, const float* __restrict__ b_ur2,
    const float* __restrict__ w_vr1, const float* __restrict__ b_vr1,
    const float* __restrict__ w_vr2, const float* __restrict__ b_vr2,
    const float* __restrict__ w_uv1, const float* __restrict__ b_uv1,
    const float* __restrict__ w_uv2, const float* __restrict__ b_uv2,
    const float* __restrict__ w_uv3, const float* __restrict__ b_uv3,
    const float* __restrict__ bn1_g, const float* __restrict__ bn1_b,
    const float* __restrict__ bn1_m, const float* __restrict__ bn1_v,
    const float* __restrict__ bn2_g, const float* __restrict__ bn2_b,
    const float* __restrict__ bn2_m, const float* __restrict__ bn2_v,
    const float* __restrict__ bn3_g, const float* __restrict__ bn3_b,
    const float* __restrict__ bn3_m, const float* __restrict__ bn3_v,
    const float* __restrict__ bn4_g, const float* __restrict__ bn4_b,
    const float* __restrict__ bn4_m, const float* __restrict__ bn4_v,
    const int* __restrict__ nodes_v, const int* __restrict__ nbr_idx,
    const int* __restrict__ nbr_len,
    float* __restrict__ out_score, float* __restrict__ ws_d2,
    float* __restrict__ ws_c) {
    const int w = threadIdx.x >> 6;
    const int lane = threadIdx.x & 63;
    const int row = blockIdx.x * 4 + w;

    __shared__ float xbuf[4][132];

    const int l16 = lane & 15;
    const int g = lane >> 4;            // group 0..3

    // ---- gather setup ----
    const int node = nodes_v[row];
    int len = nbr_len[row];
    if (len < 1) len = 1;
    const int lenm1 = len - 1;
    const f4 vq = __builtin_nontemporal_load(
        (const f4*)(v_embed + ((size_t)node << 6)) + l16);
    const int* nb = nbr_idx + (size_t)row * KNBR;

    float dmin2 = BIGF;
    for (int k0 = 0; k0 < len; k0 += 32) {
        // slot for group g, sub-batch j: k0 + 4*j + g, clamped (min-safe dup)
        int k[8];
#pragma unroll
        for (int j = 0; j < 8; ++j) {
            int kk = k0 + 4 * j + g;
            k[j] = kk < lenm1 ? kk : lenm1;
        }
        int idx[8];
#pragma unroll
        for (int j = 0; j < 8; ++j) idx[j] = __builtin_nontemporal_load(nb + k[j]);
        f4 nv[8];
#pragma unroll
        for (int j = 0; j < 8; ++j) {
            nv[j] = __builtin_nontemporal_load(
                (const f4*)(v_embed + ((size_t)idx[j] << 6)) + l16);
        }
        float d[8];
#pragma unroll
        for (int j = 0; j < 8; ++j) d[j] = sum16(d2part4(vq, nv[j]));
#pragma unroll
        for (int j = 0; j < 8; ++j) dmin2 = fminf(dmin2, d[j]);
    }
    dmin2 = fminf(dmin2, __shfl_xor(dmin2, 16));
    dmin2 = fminf(dmin2, __shfl_xor(dmin2, 32));

    // ================= MLP + curiosity (unchanged, L1-cached) =================
    float* xw = xbuf[w];
    const size_t rb = (size_t)row * DIM + lane;
    const float u1 = u1p[rb], u2 = u2p[rb], u3 = u3p[rb], u4 = u4p[rb];
    const float ev = evp[rb];

    float d12 = u1 - u2, d23 = u2 - u3, d34 = u3 - u4;
    float s1 = d12 * d12, s2 = d23 * d23, s3 = d34 * d34;
#pragma unroll
    for (int m = 1; m < 64; m <<= 1) {
        s1 += __shfl_xor(s1, m);
        s2 += __shfl_xor(s2, m);
        s3 += __shfl_xor(s3, m);
    }
    const float cval = (sqrtf(s1) + sqrtf(s2) + sqrtf(s3)) * (1.0f / 3.0f);

    float eu = u1 * 0.032058603280084993f;
    eu = fmaf(u2, 0.087144318742032567f, eu);
    eu = fmaf(u3, 0.236882818089910134f, eu);
    eu = fmaf(u4, 0.643914259887972245f, eu);

    xw[lane] = eu;
    float t1 = matvec64(xw, w_ur1, lane) + b_ur1[lane];
    t1 = (t1 - bn1_m[lane]) * rsqrtf(bn1_v[lane] + BN_EPS) * bn1_g[lane] + bn1_b[lane];
    t1 = fmaxf(t1, 0.f);
    xw[lane] = t1;
    const float xu = matvec64(xw, w_ur2, lane) + b_ur2[lane];
    xw[lane] = ev;
    float t2 = matvec64(xw, w_vr1, lane) + b_vr1[lane];
    t2 = (t2 - bn2_m[lane]) * rsqrtf(bn2_v[lane] + BN_EPS) * bn2_g[lane] + bn2_b[lane];
    t2 = fmaxf(t2, 0.f);
    xw[lane] = t2;
    const float xv = matvec64(xw, w_vr2, lane) + b_vr2[lane];
    xw[lane] = xu;
    xw[64 + lane] = xv;
    float t3 = matvec128(xw, w_uv1, lane) + b_uv1[lane];
    t3 = (t3 - bn3_m[lane]) * rsqrtf(bn3_v[lane] + BN_EPS) * bn3_g[lane] + bn3_b[lane];
    t3 = fmaxf(t3, 0.f);
    xw[lane] = t3;
    const int jj = lane & 15;
    const int q = lane >> 4;
    float h4 = 0.f;
#pragma unroll
    for (int i = 0; i < 16; ++i) {
        h4 = fmaf(xw[q * 16 + i], w_uv2[(q * 16 + i) * 16 + jj], h4);
    }
    h4 += __shfl_xor(h4, 16);
    h4 += __shfl_xor(h4, 32);
    h4 += b_uv2[jj];
    h4 = (h4 - bn4_m[jj]) * rsqrtf(bn4_v[jj] + BN_EPS) * bn4_g[jj] + bn4_b[jj];
    h4 = fmaxf(h4, 0.f);
    float p = h4 * w_uv3[jj];
#pragma unroll
    for (int m = 1; m < 16; m <<= 1) p += __shfl_xor(p, m);
    const float score = p + b_uv3[0];

    if (lane == 0) {
        out_score[row] = score;
        ws_d2[row] = dmin2;
        ws_c[row] = cval;
    }
}

// ---------- final combine: single block, global min/max + outputs ----------
__global__ __launch_bounds__(1024) void combine(
    const float* __restrict__ ws_d2, const float* __restrict__ ws_c,
    float* __restrict__ out) {
    const int tid = threadIdx.x;
    __shared__ float red[4][16];

    float ld2[8], lc[8];
    float dmin = BIGF, dmax = -BIGF, cmin = BIGF, cmax = -BIGF;
#pragma unroll
    for (int i = 0; i < 8; ++i) {
        const int b = tid * 8 + i;  // 1024 * 8 == 8192
        ld2[i] = ws_d2[b];
        lc[i] = ws_c[b];
        dmin = fminf(dmin, ld2[i]);
        dmax = fmaxf(dmax, ld2[i]);
        cmin = fminf(cmin, lc[i]);
        cmax = fmaxf(cmax, lc[i]);
    }
#pragma unroll
    for (int m = 1; m < 64; m <<= 1) {
        dmin = fminf(dmin, __shfl_xor(dmin, m));
        dmax = fmaxf(dmax, __shfl_xor(dmax, m));
        cmin = fminf(cmin, __shfl_xor(cmin, m));
        cmax = fmaxf(cmax, __shfl_xor(cmax, m));
    }
    const int wid = tid >> 6;
    const int lane = tid & 63;
    if (lane == 0) {
        red[0][wid] = dmin;
        red[1][wid] = dmax;
        red[2][wid] = cmin;
        red[3][wid] = cmax;
    }
    __syncthreads();
    dmin = red[0][0]; dmax = red[1][0]; cmin = red[2][0]; cmax = red[3][0];
#pragma unroll
    for (int i = 1; i < 16; ++i) {
        dmin = fminf(dmin, red[0][i]);
        dmax = fmaxf(dmax, red[1][i]);
        cmin = fminf(cmin, red[2][i]);
        cmax = fmaxf(cmax, red[3][i]);
    }
    const float dlo = sqrtf(dmin);
    const float dhi = sqrtf(dmax);
    const float inv_d = 1.f / (dhi - dlo);
    const float inv_c = 1.f / (cmax - cmin);
#pragma unroll
    for (int i = 0; i < 8; ++i) {
        const int b = tid * 8 + i;
        const float t = (sqrtf(ld2[i]) - dlo) * inv_d;
        const float unexp = 6.f * t * expf(-6.f * t);
        out[b] += unexp * (lc[i] - cmin) * inv_c;
    }
}

extern "C" void kernel_launch(void* const* d_in, const int* in_sizes, int n_in,
                              void* d_out, int out_size, void* d_ws, size_t ws_size,
                              hipStream_t stream) {
    const float* v_embed = (const float*)d_in[0];
    const float* u1 = (const float*)d_in[1];
    const float* u2 = (const float*)d_in[2];
    const float* u3 = (const float*)d_in[3];
    const float* u4 = (const float*)d_in[4];
    const float* ev = (const float*)d_in[5];
    const float* w_ur1 = (const float*)d_in[6];
    const float* b_ur1 = (const float*)d_in[7];
    const float* w_ur2 = (const float*)d_in[8];
    const float* b_ur2 = (const float*)d_in[9];
    const float* w_vr1 = (const float*)d_in[10];
    const float* b_vr1 = (const float*)d_in[11];
    const float* w_vr2 = (const float*)d_in[12];
    const float* b_vr2 = (const float*)d_in[13];
    const float* w_uv1 = (const float*)d_in[14];
    const float* b_uv1 = (const float*)d_in[15];
    const float* w_uv2 = (const float*)d_in[16];
    const float* b_uv2 = (const float*)d_in[17];
    const float* w_uv3 = (const float*)d_in[18];
    const float* b_uv3 = (const float*)d_in[19];
    const int* nodes_v = (const int*)d_in[20];
    const int* nbr_idx = (const int*)d_in[21];
    const int* nbr_len = (const int*)d_in[22];
    const float* bn1_g = (const float*)d_in[23];
    const float* bn1_b = (const float*)d_in[24];
    const float* bn1_m = (const float*)d_in[25];
    const float* bn1_v = (const float*)d_in[26];
    const float* bn2_g = (const float*)d_in[27];
    const float* bn2_b = (const float*)d_in[28];
    const float* bn2_m = (const float*)d_in[29];
    const float* bn2_v = (const float*)d_in[30];
    const float* bn3_g = (const float*)d_in[31];
    const float* bn3_b = (const float*)d_in[32];
    const float* bn3_m = (const float*)d_in[33];
    const float* bn3_v = (const float*)d_in[34];
    const float* bn4_g = (const float*)d_in[35];
    const float* bn4_b = (const float*)d_in[36];
    const float* bn4_m = (const float*)d_in[37];
    const float* bn4_v = (const float*)d_in[38];

    float* out = (float*)d_out;
    float* wsf = (float*)d_ws;
    float* ws_d2 = wsf;
    float* ws_c = wsf + NROWS;

    hipLaunchKernelGGL(fused_rows, dim3(NROWS / 4), dim3(256), 0, stream,
                       v_embed, u1, u2, u3, u4, ev,
                       w_ur1, b_ur1, w_ur2, b_ur2, w_vr1, b_vr1, w_vr2, b_vr2,
                       w_uv1, b_uv1, w_uv2, b_uv2, w_uv3, b_uv3,
                       bn1_g, bn1_b, bn1_m, bn1_v,
                       bn2_g, bn2_b, bn2_m, bn2_v,
                       bn3_g, bn3_b, bn3_m, bn3_v,
                       bn4_g, bn4_b, bn4_m, bn4_v,
                       nodes_v, nbr_idx, nbr_len,
                       out, ws_d2, ws_c);
    hipLaunchKernelGGL(combine, dim3(1), dim3(1024), 0, stream,
                       ws_d2, ws_c, out);
}

// Round 14
// 62.066 us; speedup vs baseline: 1.2960x; 1.2960x over previous
//
#include <hip/hip_runtime.h>
#include <math.h>

#define NROWS 8192
#define DIM 64
#define KNBR 200
#define BN_EPS 1e-5f
#define BIGF 3.402823466e38f

// ---------- wave-level helpers (wave = 64 lanes) ----------

__device__ __forceinline__ float matvec64(const float* xlds,
                                          const float* __restrict__ W,
                                          int lane) {
    float acc = 0.f;
#pragma unroll
    for (int i4 = 0; i4 < 16; ++i4) {
        float4 xv = *(const float4*)(xlds + i4 * 4);
        acc = fmaf(xv.x, W[(i4 * 4 + 0) * 64 + lane], acc);
        acc = fmaf(xv.y, W[(i4 * 4 + 1) * 64 + lane], acc);
        acc = fmaf(xv.z, W[(i4 * 4 + 2) * 64 + lane], acc);
        acc = fmaf(xv.w, W[(i4 * 4 + 3) * 64 + lane], acc);
    }
    return acc;
}

__device__ __forceinline__ float matvec128(const float* xlds,
                                           const float* __restrict__ W,
                                           int lane) {
    float acc = 0.f;
#pragma unroll
    for (int i4 = 0; i4 < 32; ++i4) {
        float4 xv = *(const float4*)(xlds + i4 * 4);
        acc = fmaf(xv.x, W[(i4 * 4 + 0) * 64 + lane], acc);
        acc = fmaf(xv.y, W[(i4 * 4 + 1) * 64 + lane], acc);
        acc = fmaf(xv.z, W[(i4 * 4 + 2) * 64 + lane], acc);
        acc = fmaf(xv.w, W[(i4 * 4 + 3) * 64 + lane], acc);
    }
    return acc;
}

__device__ __forceinline__ float d2part(const float4 a, const float4 b) {
    const float dx = a.x - b.x, dy = a.y - b.y, dz = a.z - b.z, dw = a.w - b.w;
    float d2 = dx * dx;
    d2 = fmaf(dy, dy, d2);
    d2 = fmaf(dz, dz, d2);
    d2 = fmaf(dw, dw, d2);
    return d2;
}

__device__ __forceinline__ float sum16(float v) {
    v += __shfl_xor(v, 1);
    v += __shfl_xor(v, 2);
    v += __shfl_xor(v, 4);
    v += __shfl_xor(v, 8);
    return v;
}

// ---------- fused kernel: one wave per row (R6 structure, session best) ----------
// Gather layout (TA-optimal): 16 lanes own one neighbor (4 lines/group,
// 16 lines per instruction). 32 neighbors in flight per iteration
// (8 gather instructions = 128 lines). Out-of-range slots CLAMP to the
// last valid neighbor -- a duplicated valid distance, min-safe -- so the
// inner loop has no masking logic at all.
// NOTE: L1 default caching is intentional -- R13 measured nontemporal loads
// at +17 us (L1 serves ~20-25% of gather lines + coalescing).
__global__ __launch_bounds__(256) void fused_rows(
    const float* __restrict__ v_embed,
    const float* __restrict__ u1p, const float* __restrict__ u2p,
    const float* __restrict__ u3p, const float* __restrict__ u4p,
    const float* __restrict__ evp,
    const float* __restrict__ w_ur1, const float* __restrict__ b_ur1,
    const float* __restrict__ w_ur2, const float* __restrict__ b_ur2,
    const float* __restrict__ w_vr1, const float* __restrict__ b_vr1,
    const float* __restrict__ w_vr2, const float* __restrict__ b_vr2,
    const float* __restrict__ w_uv1, const float* __restrict__ b_uv1,
    const float* __restrict__ w_uv2, const float* __restrict__ b_uv2,
    const float* __restrict__ w_uv3, const float* __restrict__ b_uv3,
    const float* __restrict__ bn1_g, const float* __restrict__ bn1_b,
    const float* __restrict__ bn1_m, const float* __restrict__ bn1_v,
    const float* __restrict__ bn2_g, const float* __restrict__ bn2_b,
    const float* __restrict__ bn2_m, const float* __restrict__ bn2_v,
    const float* __restrict__ bn3_g, const float* __restrict__ bn3_b,
    const float* __restrict__ bn3_m, const float* __restrict__ bn3_v,
    const float* __restrict__ bn4_g, const float* __restrict__ bn4_b,
    const float* __restrict__ bn4_m, const float* __restrict__ bn4_v,
    const int* __restrict__ nodes_v, const int* __restrict__ nbr_idx,
    const int* __restrict__ nbr_len,
    float* __restrict__ out_score, float* __restrict__ ws_d2,
    float* __restrict__ ws_c) {
    const int w = threadIdx.x >> 6;
    const int lane = threadIdx.x & 63;
    const int row = blockIdx.x * 4 + w;

    __shared__ float xbuf[4][132];

    const int l16 = lane & 15;
    const int g = lane >> 4;            // group 0..3

    // ---- gather setup ----
    const int node = nodes_v[row];
    int len = nbr_len[row];
    if (len < 1) len = 1;
    const int lenm1 = len - 1;
    const float4 vq = ((const float4*)(v_embed + ((size_t)node << 6)))[l16];
    const int* nb = nbr_idx + (size_t)row * KNBR;

    float dmin2 = BIGF;
    for (int k0 = 0; k0 < len; k0 += 32) {
        // slot for group g, sub-batch j: k0 + 4*j + g, clamped (min-safe dup)
        int k[8];
#pragma unroll
        for (int j = 0; j < 8; ++j) {
            int kk = k0 + 4 * j + g;
            k[j] = kk < lenm1 ? kk : lenm1;
        }
        int idx[8];
#pragma unroll
        for (int j = 0; j < 8; ++j) idx[j] = nb[k[j]];
        float4 nv[8];
#pragma unroll
        for (int j = 0; j < 8; ++j) {
            nv[j] = ((const float4*)(v_embed + ((size_t)idx[j] << 6)))[l16];
        }
        float d[8];
#pragma unroll
        for (int j = 0; j < 8; ++j) d[j] = sum16(d2part(vq, nv[j]));
#pragma unroll
        for (int j = 0; j < 8; ++j) dmin2 = fminf(dmin2, d[j]);
    }
    dmin2 = fminf(dmin2, __shfl_xor(dmin2, 16));
    dmin2 = fminf(dmin2, __shfl_xor(dmin2, 32));

    // ================= MLP + curiosity =================
    float* xw = xbuf[w];
    const size_t rb = (size_t)row * DIM + lane;
    const float u1 = u1p[rb], u2 = u2p[rb], u3 = u3p[rb], u4 = u4p[rb];
    const float ev = evp[rb];

    float d12 = u1 - u2, d23 = u2 - u3, d34 = u3 - u4;
    float s1 = d12 * d12, s2 = d23 * d23, s3 = d34 * d34;
#pragma unroll
    for (int m = 1; m < 64; m <<= 1) {
        s1 += __shfl_xor(s1, m);
        s2 += __shfl_xor(s2, m);
        s3 += __shfl_xor(s3, m);
    }
    const float cval = (sqrtf(s1) + sqrtf(s2) + sqrtf(s3)) * (1.0f / 3.0f);

    float eu = u1 * 0.032058603280084993f;
    eu = fmaf(u2, 0.087144318742032567f, eu);
    eu = fmaf(u3, 0.236882818089910134f, eu);
    eu = fmaf(u4, 0.643914259887972245f, eu);

    xw[lane] = eu;
    float t1 = matvec64(xw, w_ur1, lane) + b_ur1[lane];
    t1 = (t1 - bn1_m[lane]) * rsqrtf(bn1_v[lane] + BN_EPS) * bn1_g[lane] + bn1_b[lane];
    t1 = fmaxf(t1, 0.f);
    xw[lane] = t1;
    const float xu = matvec64(xw, w_ur2, lane) + b_ur2[lane];
    xw[lane] = ev;
    float t2 = matvec64(xw, w_vr1, lane) + b_vr1[lane];
    t2 = (t2 - bn2_m[lane]) * rsqrtf(bn2_v[lane] + BN_EPS) * bn2_g[lane] + bn2_b[lane];
    t2 = fmaxf(t2, 0.f);
    xw[lane] = t2;
    const float xv = matvec64(xw, w_vr2, lane) + b_vr2[lane];
    xw[lane] = xu;
    xw[64 + lane] = xv;
    float t3 = matvec128(xw, w_uv1, lane) + b_uv1[lane];
    t3 = (t3 - bn3_m[lane]) * rsqrtf(bn3_v[lane] + BN_EPS) * bn3_g[lane] + bn3_b[lane];
    t3 = fmaxf(t3, 0.f);
    xw[lane] = t3;
    const int jj = lane & 15;
    const int q = lane >> 4;
    float h4 = 0.f;
#pragma unroll
    for (int i = 0; i < 16; ++i) {
        h4 = fmaf(xw[q * 16 + i], w_uv2[(q * 16 + i) * 16 + jj], h4);
    }
    h4 += __shfl_xor(h4, 16);
    h4 += __shfl_xor(h4, 32);
    h4 += b_uv2[jj];
    h4 = (h4 - bn4_m[jj]) * rsqrtf(bn4_v[jj] + BN_EPS) * bn4_g[jj] + bn4_b[jj];
    h4 = fmaxf(h4, 0.f);
    float p = h4 * w_uv3[jj];
#pragma unroll
    for (int m = 1; m < 16; m <<= 1) p += __shfl_xor(p, m);
    const float score = p + b_uv3[0];

    if (lane == 0) {
        out_score[row] = score;
        ws_d2[row] = dmin2;
        ws_c[row] = cval;
    }
}

// ---------- final combine: single block, global min/max + outputs ----------
__global__ __launch_bounds__(1024) void combine(
    const float* __restrict__ ws_d2, const float* __restrict__ ws_c,
    float* __restrict__ out) {
    const int tid = threadIdx.x;
    __shared__ float red[4][16];

    float ld2[8], lc[8];
    float dmin = BIGF, dmax = -BIGF, cmin = BIGF, cmax = -BIGF;
#pragma unroll
    for (int i = 0; i < 8; ++i) {
        const int b = tid * 8 + i;  // 1024 * 8 == 8192
        ld2[i] = ws_d2[b];
        lc[i] = ws_c[b];
        dmin = fminf(dmin, ld2[i]);
        dmax = fmaxf(dmax, ld2[i]);
        cmin = fminf(cmin, lc[i]);
        cmax = fmaxf(cmax, lc[i]);
    }
#pragma unroll
    for (int m = 1; m < 64; m <<= 1) {
        dmin = fminf(dmin, __shfl_xor(dmin, m));
        dmax = fmaxf(dmax, __shfl_xor(dmax, m));
        cmin = fminf(cmin, __shfl_xor(cmin, m));
        cmax = fmaxf(cmax, __shfl_xor(cmax, m));
    }
    const int wid = tid >> 6;
    const int lane = tid & 63;
    if (lane == 0) {
        red[0][wid] = dmin;
        red[1][wid] = dmax;
        red[2][wid] = cmin;
        red[3][wid] = cmax;
    }
    __syncthreads();
    dmin = red[0][0]; dmax = red[1][0]; cmin = red[2][0]; cmax = red[3][0];
#pragma unroll
    for (int i = 1; i < 16; ++i) {
        dmin = fminf(dmin, red[0][i]);
        dmax = fmaxf(dmax, red[1][i]);
        cmin = fminf(cmin, red[2][i]);
        cmax = fmaxf(cmax, red[3][i]);
    }
    const float dlo = sqrtf(dmin);
    const float dhi = sqrtf(dmax);
    const float inv_d = 1.f / (dhi - dlo);
    const float inv_c = 1.f / (cmax - cmin);
#pragma unroll
    for (int i = 0; i < 8; ++i) {
        const int b = tid * 8 + i;
        const float t = (sqrtf(ld2[i]) - dlo) * inv_d;
        const float unexp = 6.f * t * expf(-6.f * t);
        out[b] += unexp * (lc[i] - cmin) * inv_c;
    }
}

extern "C" void kernel_launch(void* const* d_in, const int* in_sizes, int n_in,
                              void* d_out, int out_size, void* d_ws, size_t ws_size,
                              hipStream_t stream) {
    const float* v_embed = (const float*)d_in[0];
    const float* u1 = (const float*)d_in[1];
    const float* u2 = (const float*)d_in[2];
    const float* u3 = (const float*)d_in[3];
    const float* u4 = (const float*)d_in[4];
    const float* ev = (const float*)d_in[5];
    const float* w_ur1 = (const float*)d_in[6];
    const float* b_ur1 = (const float*)d_in[7];
    const float* w_ur2 = (const float*)d_in[8];
    const float* b_ur2 = (const float*)d_in[9];
    const float* w_vr1 = (const float*)d_in[10];
    const float* b_vr1 = (const float*)d_in[11];
    const float* w_vr2 = (const float*)d_in[12];
    const float* b_vr2 = (const float*)d_in[13];
    const float* w_uv1 = (const float*)d_in[14];
    const float* b_uv1 = (const float*)d_in[15];
    const float* w_uv2 = (const float*)d_in[16];
    const float* b_uv2 = (const float*)d_in[17];
    const float* w_uv3 = (const float*)d_in[18];
    const float* b_uv3 = (const float*)d_in[19];
    const int* nodes_v = (const int*)d_in[20];
    const int* nbr_idx = (const int*)d_in[21];
    const int* nbr_len = (const int*)d_in[22];
    const float* bn1_g = (const float*)d_in[23];
    const float* bn1_b = (const float*)d_in[24];
    const float* bn1_m = (const float*)d_in[25];
    const float* bn1_v = (const float*)d_in[26];
    const float* bn2_g = (const float*)d_in[27];
    const float* bn2_b = (const float*)d_in[28];
    const float* bn2_m = (const float*)d_in[29];
    const float* bn2_v = (const float*)d_in[30];
    const float* bn3_g = (const float*)d_in[31];
    const float* bn3_b = (const float*)d_in[32];
    const float* bn3_m = (const float*)d_in[33];
    const float* bn3_v = (const float*)d_in[34];
    const float* bn4_g = (const float*)d_in[35];
    const float* bn4_b = (const float*)d_in[36];
    const float* bn4_m = (const float*)d_in[37];
    const float* bn4_v = (const float*)d_in[38];

    float* out = (float*)d_out;
    float* wsf = (float*)d_ws;
    float* ws_d2 = wsf;
    float* ws_c = wsf + NROWS;

    hipLaunchKernelGGL(fused_rows, dim3(NROWS / 4), dim3(256), 0, stream,
                       v_embed, u1, u2, u3, u4, ev,
                       w_ur1, b_ur1, w_ur2, b_ur2, w_vr1, b_vr1, w_vr2, b_vr2,
                       w_uv1, b_uv1, w_uv2, b_uv2, w_uv3, b_uv3,
                       bn1_g, bn1_b, bn1_m, bn1_v,
                       bn2_g, bn2_b, bn2_m, bn2_v,
                       bn3_g, bn3_b, bn3_m, bn3_v,
                       bn4_g, bn4_b, bn4_m, bn4_v,
                       nodes_v, nbr_idx, nbr_len,
                       out, ws_d2, ws_c);
    hipLaunchKernelGGL(combine, dim3(1), dim3(1024), 0, stream,
                       ws_d2, ws_c, out);
}